// Round 1
// baseline (384.318 us; speedup 1.0000x reference)
//
#include <hip/hip_runtime.h>
#include <hip/hip_bf16.h>
#include <math.h>

#define NSPH 7
#define NRAD 6
#define NJ 42            // NSPH*NRAD
#define PAD_STRIDE 44    // floats per table row (16B aligned: 44*4=176)
#define S2B 256          // triplets per stage-2 block

struct K1C {
  double Z[NJ];   // bessel zeros z_{l,n}
  double IZ[NJ];  // 1/z
  double NY[NJ];  // NORM[l,n] * Y_NORM[l]  (Y_NORM folded into table)
};

// ---------------- device: bounded-range f64 sincos (0 < a <= ~27) -------------
__device__ __forceinline__ void sincos_d(double a, double& s, double& c) {
  const double TWO_OVER_PI = 0.6366197723675814;
  double kd = rint(a * TWO_OVER_PI);
  int q = (int)kd;
  const double P1 = 1.5707963267948966;     // pi/2 hi
  const double P2 = 6.123233995736766e-17;  // pi/2 lo
  double r = fma(-kd, P1, a);
  r = fma(-kd, P2, r);
  double r2 = r * r;
  // sin Taylor to r^11 (|r|<=pi/4, err ~7e-12)
  double ss = r * fma(r2, fma(r2, fma(r2, fma(r2, fma(r2,
      -2.505210838544172e-08, 2.7557319223985893e-06),
      -1.984126984126984e-04), 8.333333333333333e-03),
      -0.16666666666666666), 1.0);
  // cos Taylor to r^10 (err ~1e-10)
  double cc = fma(r2, fma(r2, fma(r2, fma(r2, fma(r2,
      -2.755731922398589e-07, 2.48015873015873e-05),
      -1.3888888888888889e-03), 0.041666666666666664),
      -0.5), 1.0);
  double s_ = (q & 1) ? cc : ss;
  double c_ = (q & 1) ? ss : cc;
  if (q & 2) s_ = -s_;
  if ((q + 1) & 2) c_ = -c_;
  s = s_; c = c_;
}

// env(d) * NORM * Y_NORM * j_l(z*x) for all 42 (l,n), f64 recurrence
__device__ __forceinline__ void compute_row(double dd, const K1C& C, float* row) {
  double x = dd * 0.2;          // d / CUTOFF, CUTOFF == ENVELOPE_CUTOFF == 5
  double invx = 1.0 / x;
  double u2 = x * x;
  double u4 = u2 * u2;
  double u5 = u4 * x;
  // env = 1/u - 28 u^5 + 48 u^6 - 21 u^7  (p = 6)
  double env = invx + u5 * fma(x, fma(x, -21.0, 48.0), -28.0);
  if (x >= 1.0) env = 0.0;
  #pragma unroll
  for (int l = 0; l < NSPH; ++l) {
    #pragma unroll
    for (int n = 0; n < NRAD; ++n) {
      const int i = l * NRAD + n;
      double a = C.Z[i] * x;
      double s, c;
      sincos_d(a, s, c);
      double inva = C.IZ[i] * invx;
      double j0 = s * inva;
      double jl;
      if (l == 0) {
        jl = j0;
      } else {
        double j1 = (j0 - c) * inva;
        #pragma unroll
        for (int m = 2; m <= l; ++m) {
          double jn_ = (2 * m - 1) * inva * j1 - j0;
          j0 = j1; j1 = jn_;
        }
        jl = j1;
      }
      row[i] = (float)(env * C.NY[i] * jl);
    }
  }
}

// ---------------- stage 1: per-edge table build -------------------------------
__global__ void __launch_bounds__(256) k_stage1(const float* __restrict__ d,
                                                float* __restrict__ rbf,
                                                int E, int stride, K1C C) {
  int e = blockIdx.x * blockDim.x + threadIdx.x;
  if (e >= E) return;
  alignas(16) float v[NJ];
  compute_row((double)d[e], C, v);
  float* base = rbf + (size_t)e * stride;
  if (stride == PAD_STRIDE) {            // 16B-aligned rows -> float4 stores
    #pragma unroll
    for (int i = 0; i < 10; ++i)
      *(float4*)(base + 4 * i) = *(const float4*)(v + 4 * i);
    *(float2*)(base + 40) = *(const float2*)(v + 40);
  } else {                               // 8B-aligned rows -> float2 stores
    #pragma unroll
    for (int i = 0; i < 21; ++i)
      *(float2*)(base + 2 * i) = *(const float2*)(v + 2 * i);
  }
}

// ---------------- stage 2: gather + Legendre multiply -------------------------
__global__ void __launch_bounds__(S2B) k_stage2(const float* __restrict__ ang,
                                                const int* __restrict__ idx,
                                                const float* __restrict__ rbf,
                                                float* __restrict__ out,
                                                int T, int stride) {
  __shared__ float s_cbf[S2B][8];
  __shared__ int s_base[S2B];
  const int tid = threadIdx.x;
  const int t0 = blockIdx.x * S2B;
  const int t = t0 + tid;
  if (t < T) {
    float cth = cosf(ang[t]);
    float p0 = 1.f, p1 = cth;
    s_cbf[tid][0] = 1.f;
    s_cbf[tid][1] = cth;
    #pragma unroll
    for (int l = 2; l < NSPH; ++l) {
      float pn = ((2 * l - 1) * cth * p1 - (l - 1) * p0) / (float)l;
      s_cbf[tid][l] = pn;
      p0 = p1; p1 = pn;
    }
    s_base[tid] = idx[t] * stride;
  }
  __syncthreads();
  float* ob = out + (size_t)t0 * NJ;
  #pragma unroll
  for (int k = 0; k < 21; ++k) {
    int w = k * S2B + tid;               // work item: out float2 index
    int tl = w / 21;                     // local triplet
    int jp = w - tl * 21;                // float2 pair within row
    if (t0 + tl < T) {
      int l = jp / 3;                    // = (2*jp)/6; pairs never straddle l
      const float2 r = *(const float2*)(rbf + s_base[tl] + 2 * jp);
      float m = s_cbf[tl][l];
      float2 ov; ov.x = r.x * m; ov.y = r.y * m;
      *(float2*)(ob + 2 * w) = ov;       // t0*42 + 2w : fully coalesced
    }
  }
}

// ---------------- fused fallback (only if d_ws too small) ---------------------
__global__ void __launch_bounds__(256) k_fused(const float* __restrict__ d,
                                               const float* __restrict__ ang,
                                               const int* __restrict__ idx,
                                               float* __restrict__ out,
                                               int T, K1C C) {
  int t = blockIdx.x * blockDim.x + threadIdx.x;
  if (t >= T) return;
  alignas(16) float v[NJ];
  compute_row((double)d[idx[t]], C, v);
  float cth = cosf(ang[t]);
  float P[NSPH];
  P[0] = 1.f; P[1] = cth;
  #pragma unroll
  for (int l = 2; l < NSPH; ++l)
    P[l] = ((2 * l - 1) * cth * P[l - 1] - (l - 1) * P[l - 2]) / (float)l;
  float* o = out + (size_t)t * NJ;
  #pragma unroll
  for (int i = 0; i < NJ; ++i) o[i] = v[i] * P[i / 6];
}

// ---------------- host: bessel zeros / norms (f64, deterministic) -------------
static double jn_host(int l, double x) {
  double j0 = sin(x) / x;
  if (l == 0) return j0;
  double j1 = sin(x) / (x * x) - cos(x) / x;
  for (int i = 2; i <= l; ++i) {
    double jn_ = (2 * i - 1) / x * j1 - j0;
    j0 = j1; j1 = jn_;
  }
  return j1;
}

extern "C" void kernel_launch(void* const* d_in, const int* in_sizes, int n_in,
                              void* d_out, int out_size, void* d_ws, size_t ws_size,
                              hipStream_t stream) {
  const float* d   = (const float*)d_in[0];
  const float* ang = (const float*)d_in[1];
  const int*   idx = (const int*)d_in[2];
  float* out = (float*)d_out;
  const int E = in_sizes[0];
  const int T = in_sizes[1];

  // --- constants (recomputed every call; deterministic, ~us of CPU) ---
  K1C C;
  {
    const double PI = 3.14159265358979323846;
    double zeros[NSPH][NRAD];
    double prev[NSPH + NRAD - 1];
    int np_ = NSPH + NRAD - 1;
    for (int i = 0; i < np_; ++i) prev[i] = (i + 1) * PI;
    for (int j = 0; j < NRAD; ++j) zeros[0][j] = prev[j];
    for (int l = 1; l < NSPH; ++l) {
      int nc = np_ - 1;
      double cur[NSPH + NRAD - 1];
      for (int i = 0; i < nc; ++i) {
        double a = prev[i], b = prev[i + 1];
        double fa = jn_host(l, a);
        for (int it = 0; it < 80; ++it) {
          double m = 0.5 * (a + b);
          double fm = jn_host(l, m);
          if ((fm > 0.0) == (fa > 0.0)) { a = m; fa = fm; } else { b = m; }
        }
        cur[i] = 0.5 * (a + b);
      }
      for (int i = 0; i < nc; ++i) prev[i] = cur[i];
      np_ = nc;
      for (int j = 0; j < NRAD; ++j) zeros[l][j] = prev[j];
    }
    for (int l = 0; l < NSPH; ++l) {
      double yn = sqrt((2.0 * l + 1.0) / (4.0 * PI));
      for (int n = 0; n < NRAD; ++n) {
        int i = l * NRAD + n;
        double z = zeros[l][n];
        C.Z[i] = z;
        C.IZ[i] = 1.0 / z;
        C.NY[i] = sqrt(2.0) / fabs(jn_host(l + 1, z)) * yn;
      }
    }
  }

  const size_t need44 = (size_t)E * PAD_STRIDE * sizeof(float);
  const size_t need42 = (size_t)E * NJ * sizeof(float);
  if (ws_size >= need42) {
    const int stride = (ws_size >= need44) ? PAD_STRIDE : NJ;
    float* rbf = (float*)d_ws;
    k_stage1<<<(E + 255) / 256, 256, 0, stream>>>(d, rbf, E, stride, C);
    k_stage2<<<(T + S2B - 1) / S2B, S2B, 0, stream>>>(ang, idx, rbf, out, T, stride);
  } else {
    k_fused<<<(T + 255) / 256, 256, 0, stream>>>(d, ang, idx, out, T, C);
  }
}

// Round 2
// 303.595 us; speedup vs baseline: 1.2659x; 1.2659x over previous
//
#include <hip/hip_runtime.h>
#include <hip/hip_bf16.h>
#include <hip/hip_fp16.h>
#include <math.h>

#define NSPH 7
#define NRAD 6
#define NJ 42            // NSPH*NRAD
#define HSTRIDE 44       // halves per table row (88 B, 8B-aligned rows)
#define S2B 256          // triplets per stage-2 block

typedef float v2f __attribute__((ext_vector_type(2)));

struct K1C {
  double Z[NJ];   // bessel zeros z_{l,n}
  double IZ[NJ];  // 1/z
  double NY[NJ];  // NORM[l,n] * Y_NORM[l]  (Y_NORM folded into table)
};

// ---------------- device: bounded-range f64 sincos (0 < a <= ~27) -------------
__device__ __forceinline__ void sincos_d(double a, double& s, double& c) {
  const double TWO_OVER_PI = 0.6366197723675814;
  double kd = rint(a * TWO_OVER_PI);
  int q = (int)kd;
  const double P1 = 1.5707963267948966;     // pi/2 hi
  const double P2 = 6.123233995736766e-17;  // pi/2 lo
  double r = fma(-kd, P1, a);
  r = fma(-kd, P2, r);
  double r2 = r * r;
  double ss = r * fma(r2, fma(r2, fma(r2, fma(r2, fma(r2,
      -2.505210838544172e-08, 2.7557319223985893e-06),
      -1.984126984126984e-04), 8.333333333333333e-03),
      -0.16666666666666666), 1.0);
  double cc = fma(r2, fma(r2, fma(r2, fma(r2, fma(r2,
      -2.755731922398589e-07, 2.48015873015873e-05),
      -1.3888888888888889e-03), 0.041666666666666664),
      -0.5), 1.0);
  double s_ = (q & 1) ? cc : ss;
  double c_ = (q & 1) ? ss : cc;
  if (q & 2) s_ = -s_;
  if ((q + 1) & 2) c_ = -c_;
  s = s_; c = c_;
}

// env(d) * NORM * Y_NORM * j_l(z*x) for all 42 (l,n), f64 recurrence
__device__ __forceinline__ void compute_row(double dd, const K1C& C, float* row) {
  double x = dd * 0.2;          // d / CUTOFF, CUTOFF == ENVELOPE_CUTOFF == 5
  double invx = 1.0 / x;
  double u2 = x * x;
  double u4 = u2 * u2;
  double u5 = u4 * x;
  // env = 1/u - 28 u^5 + 48 u^6 - 21 u^7  (p = 6)
  double env = invx + u5 * fma(x, fma(x, -21.0, 48.0), -28.0);
  if (x >= 1.0) env = 0.0;
  #pragma unroll
  for (int l = 0; l < NSPH; ++l) {
    #pragma unroll
    for (int n = 0; n < NRAD; ++n) {
      const int i = l * NRAD + n;
      double a = C.Z[i] * x;
      double s, c;
      sincos_d(a, s, c);
      double inva = C.IZ[i] * invx;
      double j0 = s * inva;
      double jl;
      if (l == 0) {
        jl = j0;
      } else {
        double j1 = (j0 - c) * inva;
        #pragma unroll
        for (int m = 2; m <= l; ++m) {
          double jn_ = (2 * m - 1) * inva * j1 - j0;
          j0 = j1; j1 = jn_;
        }
        jl = j1;
      }
      row[i] = (float)(env * C.NY[i] * jl);
    }
  }
}

// ---------------- stage 1: per-edge fp16 table build --------------------------
__global__ void __launch_bounds__(256) k_stage1(const float* __restrict__ d,
                                                __half* __restrict__ rbf,
                                                int E, K1C C) {
  int e = blockIdx.x * blockDim.x + threadIdx.x;
  if (e >= E) return;
  float v[NJ];
  compute_row((double)d[e], C, v);
  alignas(8) __half h[HSTRIDE];
  #pragma unroll
  for (int i = 0; i < NJ; ++i) h[i] = __float2half_rn(v[i]);
  h[42] = __float2half_rn(0.f);
  h[43] = __float2half_rn(0.f);
  uint2* base = (uint2*)(rbf + (size_t)e * HSTRIDE);   // 88B rows, 8B aligned
  const uint2* hv = (const uint2*)h;
  #pragma unroll
  for (int i = 0; i < 11; ++i) base[i] = hv[i];
}

// ---------------- stage 2: gather + Legendre multiply (nt stores) -------------
__global__ void __launch_bounds__(S2B) k_stage2(const float* __restrict__ ang,
                                                const int* __restrict__ idx,
                                                const __half* __restrict__ rbf,
                                                float* __restrict__ out,
                                                int T) {
  __shared__ float s_cbf[S2B][8];
  __shared__ int s_base[S2B];
  const int tid = threadIdx.x;
  const int t0 = blockIdx.x * S2B;
  const int t = t0 + tid;
  if (t < T) {
    float cth = cosf(__builtin_nontemporal_load(ang + t));
    float p0 = 1.f, p1 = cth;
    s_cbf[tid][0] = 1.f;
    s_cbf[tid][1] = cth;
    #pragma unroll
    for (int l = 2; l < NSPH; ++l) {
      float pn = ((2 * l - 1) * cth * p1 - (l - 1) * p0) / (float)l;
      s_cbf[tid][l] = pn;
      p0 = p1; p1 = pn;
    }
    s_base[tid] = __builtin_nontemporal_load(idx + t) * HSTRIDE;
  }
  __syncthreads();
  float* ob = out + (size_t)t0 * NJ;
  #pragma unroll
  for (int k = 0; k < 21; ++k) {
    int w = k * S2B + tid;               // out float2 index within block
    int tl = w / 21;                     // local triplet
    int jp = w - tl * 21;                // float2 pair within row
    if (t0 + tl < T) {
      int l = jp / 3;                    // pairs never straddle an l boundary
      const __half2 hh = *(const __half2*)(rbf + s_base[tl] + 2 * jp);
      float2 r = __half22float2(hh);
      float m = s_cbf[tl][l];
      v2f ov = {r.x * m, r.y * m};
      __builtin_nontemporal_store(ov, (v2f*)(ob + 2 * w));  // coalesced, L3-bypass
    }
  }
}

// ---------------- fused fallback (only if d_ws too small) ---------------------
__global__ void __launch_bounds__(256) k_fused(const float* __restrict__ d,
                                               const float* __restrict__ ang,
                                               const int* __restrict__ idx,
                                               float* __restrict__ out,
                                               int T, K1C C) {
  int t = blockIdx.x * blockDim.x + threadIdx.x;
  if (t >= T) return;
  float v[NJ];
  compute_row((double)d[idx[t]], C, v);
  float cth = cosf(ang[t]);
  float P[NSPH];
  P[0] = 1.f; P[1] = cth;
  #pragma unroll
  for (int l = 2; l < NSPH; ++l)
    P[l] = ((2 * l - 1) * cth * P[l - 1] - (l - 1) * P[l - 2]) / (float)l;
  float* o = out + (size_t)t * NJ;
  #pragma unroll
  for (int i = 0; i < NJ; ++i) o[i] = v[i] * P[i / 6];
}

// ---------------- host: bessel zeros / norms (f64, deterministic) -------------
static double jn_host(int l, double x) {
  double j0 = sin(x) / x;
  if (l == 0) return j0;
  double j1 = sin(x) / (x * x) - cos(x) / x;
  for (int i = 2; i <= l; ++i) {
    double jn_ = (2 * i - 1) / x * j1 - j0;
    j0 = j1; j1 = jn_;
  }
  return j1;
}

extern "C" void kernel_launch(void* const* d_in, const int* in_sizes, int n_in,
                              void* d_out, int out_size, void* d_ws, size_t ws_size,
                              hipStream_t stream) {
  const float* d   = (const float*)d_in[0];
  const float* ang = (const float*)d_in[1];
  const int*   idx = (const int*)d_in[2];
  float* out = (float*)d_out;
  const int E = in_sizes[0];
  const int T = in_sizes[1];

  // --- constants (recomputed every call; deterministic, ~us of CPU) ---
  K1C C;
  {
    const double PI = 3.14159265358979323846;
    double zeros[NSPH][NRAD];
    double prev[NSPH + NRAD - 1];
    int np_ = NSPH + NRAD - 1;
    for (int i = 0; i < np_; ++i) prev[i] = (i + 1) * PI;
    for (int j = 0; j < NRAD; ++j) zeros[0][j] = prev[j];
    for (int l = 1; l < NSPH; ++l) {
      int nc = np_ - 1;
      double cur[NSPH + NRAD - 1];
      for (int i = 0; i < nc; ++i) {
        double a = prev[i], b = prev[i + 1];
        double fa = jn_host(l, a);
        for (int it = 0; it < 80; ++it) {
          double m = 0.5 * (a + b);
          double fm = jn_host(l, m);
          if ((fm > 0.0) == (fa > 0.0)) { a = m; fa = fm; } else { b = m; }
        }
        cur[i] = 0.5 * (a + b);
      }
      for (int i = 0; i < nc; ++i) prev[i] = cur[i];
      np_ = nc;
      for (int j = 0; j < NRAD; ++j) zeros[l][j] = prev[j];
    }
    for (int l = 0; l < NSPH; ++l) {
      double yn = sqrt((2.0 * l + 1.0) / (4.0 * PI));
      for (int n = 0; n < NRAD; ++n) {
        int i = l * NRAD + n;
        double z = zeros[l][n];
        C.Z[i] = z;
        C.IZ[i] = 1.0 / z;
        C.NY[i] = sqrt(2.0) / fabs(jn_host(l + 1, z)) * yn;
      }
    }
  }

  const size_t need = (size_t)E * HSTRIDE * sizeof(__half);   // 88 MB
  if (ws_size >= need) {
    __half* rbf = (__half*)d_ws;
    k_stage1<<<(E + 255) / 256, 256, 0, stream>>>(d, rbf, E, C);
    k_stage2<<<(T + S2B - 1) / S2B, S2B, 0, stream>>>(ang, idx, rbf, out, T);
  } else {
    k_fused<<<(T + 255) / 256, 256, 0, stream>>>(d, ang, idx, out, T, C);
  }
}

// Round 3
// 207.560 us; speedup vs baseline: 1.8516x; 1.4627x over previous
//
#include <hip/hip_runtime.h>
#include <hip/hip_bf16.h>
#include <math.h>

#define NSPH 7
#define NRAD 6
#define NJ 42
#define NF32 30           // i = 0..29  -> l = 0..4 in f32
#define NF64 12           // i = 30..41 -> l = 5,6 in f64
#define ROWW 46           // LDS row stride in floats (184 B: 8B-aligned, 2-way banks)
#define BLK 256

typedef float v2f __attribute__((ext_vector_type(2)));

struct KC {
  float  zf[NF32];   // bessel zeros, f32 (l<=4)
  float  izf[NF32];  // 1/z f32
  float  nyf[NF32];  // NORM*Y_NORM f32
  double zd[NF64];   // zeros f64 (l=5,6)
  double izd[NF64];
  double nyd[NF64];
};

// ---------------- f32 Cody-Waite sincos (0 < a <= ~27) ------------------------
__device__ __forceinline__ void sincos32(float a, float& s, float& c) {
  float kf = rintf(a * 0.63661977f);
  int q = (int)kf;
  float r = fmaf(-kf, 1.5707964f, a);      // pi/2 hi (fma: exact product)
  r = fmaf(-kf, -4.3711388e-8f, r);        // pi/2 lo
  float r2 = r * r;
  float sp = fmaf(r2, 2.7557319e-6f, -1.9841270e-4f);
  sp = fmaf(r2, sp, 8.3333333e-3f);
  sp = fmaf(r2, sp, -0.16666667f);
  float ss = fmaf(r2 * r, sp, r);
  float cp = fmaf(r2, 2.4801587e-5f, -1.3888889e-3f);
  cp = fmaf(r2, cp, 4.1666668e-2f);
  cp = fmaf(r2, cp, -0.5f);
  float cc = fmaf(r2, cp, 1.0f);
  float s_ = (q & 1) ? cc : ss;
  float c_ = (q & 1) ? ss : cc;
  if (q & 2) s_ = -s_;
  if ((q + 1) & 2) c_ = -c_;
  s = s_; c = c_;
}

// ---------------- f64 sincos (verified in R1/R2) ------------------------------
__device__ __forceinline__ void sincos_d(double a, double& s, double& c) {
  double kd = rint(a * 0.6366197723675814);
  int q = (int)kd;
  double r = fma(-kd, 1.5707963267948966, a);
  r = fma(-kd, 6.123233995736766e-17, r);
  double r2 = r * r;
  double ss = r * fma(r2, fma(r2, fma(r2, fma(r2, fma(r2,
      -2.505210838544172e-08, 2.7557319223985893e-06),
      -1.984126984126984e-04), 8.333333333333333e-03),
      -0.16666666666666666), 1.0);
  double cc = fma(r2, fma(r2, fma(r2, fma(r2, fma(r2,
      -2.755731922398589e-07, 2.48015873015873e-05),
      -1.3888888888888889e-03), 0.041666666666666664),
      -0.5), 1.0);
  double s_ = (q & 1) ? cc : ss;
  double c_ = (q & 1) ? ss : cc;
  if (q & 2) s_ = -s_;
  if ((q + 1) & 2) c_ = -c_;
  s = s_; c = c_;
}

// ---------------- fused kernel ------------------------------------------------
__global__ void __launch_bounds__(BLK) k_fused(const float* __restrict__ d,
                                               const float* __restrict__ ang,
                                               const int* __restrict__ idx,
                                               float* __restrict__ out,
                                               int T, KC C) {
  __shared__ float sv[BLK * ROWW];   // 47104 B -> 3 blocks/CU
  const int tid = threadIdx.x;
  const int t0 = blockIdx.x * BLK;
  const int t = t0 + tid;

  if (t < T) {
    const int e = __builtin_nontemporal_load(idx + t);
    const float dv = d[e];                         // 4 MB array: L2/L3-resident
    const float an = __builtin_nontemporal_load(ang + t);

    const float x = dv / 5.0f;                     // matches np's d/CUTOFF in f32
    const float invx = 1.0f / x;
    // envelope: 1/u - 28u^5 + 48u^6 - 21u^7
    const float x2 = x * x;
    const float x5 = x2 * x2 * x;
    float env = invx + x5 * fmaf(x, fmaf(x, -21.0f, 48.0f), -28.0f);
    if (x >= 1.0f) env = 0.0f;

    // Legendre P_l(cos an), fold env in: mP[l] = env * P_l
    float cth, sth_unused;
    sincos32(an, sth_unused, cth);
    float mP[NSPH];
    {
      float p0 = 1.f, p1 = cth;
      mP[0] = env; mP[1] = env * cth;
      const float rl[5] = {1.f/2.f, 1.f/3.f, 1.f/4.f, 1.f/5.f, 1.f/6.f};
      #pragma unroll
      for (int l = 2; l < NSPH; ++l) {
        float pn = (fmaf((float)(2*l-1) * cth, p1, -(float)(l-1) * p0)) * rl[l-2];
        mP[l] = env * pn;
        p0 = p1; p1 = pn;
      }
    }

    float* row = sv + tid * ROWW;

    // ---- l = 0..4 in f32 ----
    #pragma unroll
    for (int l = 0; l < 5; ++l) {
      float jv[NRAD];
      #pragma unroll
      for (int n = 0; n < NRAD; ++n) {
        const int i = l * NRAD + n;
        float a = C.zf[i] * x;
        float s, c;
        sincos32(a, s, c);
        float inva = C.izf[i] * invx;
        float j0 = s * inva;
        float jl;
        if (l == 0) {
          jl = j0;
        } else {
          float j1 = (j0 - c) * inva;
          #pragma unroll
          for (int m = 2; m <= l; ++m) {
            float jn_ = fmaf((float)(2*m-1) * inva, j1, -j0);
            j0 = j1; j1 = jn_;
          }
          jl = j1;
        }
        jv[n] = (C.nyf[i] * jl) * mP[l];
      }
      v2f* dst = (v2f*)(row + l * NRAD);
      dst[0] = (v2f){jv[0], jv[1]};
      dst[1] = (v2f){jv[2], jv[3]};
      dst[2] = (v2f){jv[4], jv[5]};
    }

    // ---- l = 5,6 in f64 ----
    const double xd = (double)x;
    const double invxd = 1.0 / xd;
    #pragma unroll
    for (int l = 5; l < NSPH; ++l) {
      float jv[NRAD];
      #pragma unroll
      for (int n = 0; n < NRAD; ++n) {
        const int k = (l - 5) * NRAD + n;
        double a = C.zd[k] * xd;
        double s, c;
        sincos_d(a, s, c);
        double inva = C.izd[k] * invxd;
        double j0 = s * inva;
        double j1 = (j0 - c) * inva;
        #pragma unroll
        for (int m = 2; m <= l; ++m) {
          double jn_ = fma((double)(2*m-1) * inva, j1, -j0);
          j0 = j1; j1 = jn_;
        }
        jv[n] = (float)(j1 * C.nyd[k]) * mP[l];
      }
      v2f* dst = (v2f*)(row + l * NRAD);
      dst[0] = (v2f){jv[0], jv[1]};
      dst[1] = (v2f){jv[2], jv[3]};
      dst[2] = (v2f){jv[4], jv[5]};
    }
  }
  __syncthreads();

  // ---- coalesced output: LDS -> global, float2 lanes, nt stores ----
  v2f* obase = (v2f*)(out + (size_t)t0 * NJ);
  #pragma unroll
  for (int k = 0; k < 21; ++k) {
    unsigned w = k * BLK + tid;          // float2 index within block's output
    unsigned tl = w / 21u;               // local triplet
    unsigned jp = w - tl * 21u;          // float2 pair within row
    if ((int)(t0 + tl) < T) {
      v2f val = *(const v2f*)(sv + tl * ROWW + 2 * jp);
      __builtin_nontemporal_store(val, obase + w);
    }
  }
}

// ---------------- host: bessel zeros / norms (f64, deterministic) -------------
static double jn_host(int l, double x) {
  double j0 = sin(x) / x;
  if (l == 0) return j0;
  double j1 = sin(x) / (x * x) - cos(x) / x;
  for (int i = 2; i <= l; ++i) {
    double jn_ = (2 * i - 1) / x * j1 - j0;
    j0 = j1; j1 = jn_;
  }
  return j1;
}

extern "C" void kernel_launch(void* const* d_in, const int* in_sizes, int n_in,
                              void* d_out, int out_size, void* d_ws, size_t ws_size,
                              hipStream_t stream) {
  const float* d   = (const float*)d_in[0];
  const float* ang = (const float*)d_in[1];
  const int*   idx = (const int*)d_in[2];
  float* out = (float*)d_out;
  const int T = in_sizes[1];

  KC C;
  {
    const double PI = 3.14159265358979323846;
    double zeros[NSPH][NRAD];
    double prev[NSPH + NRAD - 1];
    int np_ = NSPH + NRAD - 1;
    for (int i = 0; i < np_; ++i) prev[i] = (i + 1) * PI;
    for (int j = 0; j < NRAD; ++j) zeros[0][j] = prev[j];
    for (int l = 1; l < NSPH; ++l) {
      int nc = np_ - 1;
      double cur[NSPH + NRAD - 1];
      for (int i = 0; i < nc; ++i) {
        double a = prev[i], b = prev[i + 1];
        double fa = jn_host(l, a);
        for (int it = 0; it < 80; ++it) {
          double m = 0.5 * (a + b);
          double fm = jn_host(l, m);
          if ((fm > 0.0) == (fa > 0.0)) { a = m; fa = fm; } else { b = m; }
        }
        cur[i] = 0.5 * (a + b);
      }
      for (int i = 0; i < nc; ++i) prev[i] = cur[i];
      np_ = nc;
      for (int j = 0; j < NRAD; ++j) zeros[l][j] = prev[j];
    }
    for (int l = 0; l < NSPH; ++l) {
      double yn = sqrt((2.0 * l + 1.0) / (4.0 * PI));
      for (int n = 0; n < NRAD; ++n) {
        double z = zeros[l][n];
        double ny = sqrt(2.0) / fabs(jn_host(l + 1, z)) * yn;
        if (l < 5) {
          int i = l * NRAD + n;
          C.zf[i]  = (float)z;
          C.izf[i] = (float)(1.0 / z);
          C.nyf[i] = (float)ny;
        } else {
          int k = (l - 5) * NRAD + n;
          C.zd[k]  = z;
          C.izd[k] = 1.0 / z;
          C.nyd[k] = ny;
        }
      }
    }
  }

  k_fused<<<(T + BLK - 1) / BLK, BLK, 0, stream>>>(d, ang, idx, out, T, C);
}

// Round 4
// 183.177 us; speedup vs baseline: 2.0981x; 1.1331x over previous
//
#include <hip/hip_runtime.h>
#include <hip/hip_bf16.h>
#include <hip/hip_fp16.h>
#include <math.h>

#define NSPH 7
#define NRAD 6
#define NJ 42
#define NF32 30           // l = 0..4 in f32 (HW trig)
#define NF64 12           // l = 5,6 in f64 (recurrence amplification ~1e4)
#define ROWH 46           // LDS row stride in halves (92 B; 23 banks -> conflict-free)
#define BLK 256

typedef float v2f __attribute__((ext_vector_type(2)));

struct KC {
  float  zf[NF32];
  float  izf[NF32];
  float  nyf[NF32];
  double zd[NF64];
  double izd[NF64];
  double nyd[NF64];
};

// ---------------- f64 sincos (verified R1-R3) ---------------------------------
__device__ __forceinline__ void sincos_d(double a, double& s, double& c) {
  double kd = rint(a * 0.6366197723675814);
  int q = (int)kd;
  double r = fma(-kd, 1.5707963267948966, a);
  r = fma(-kd, 6.123233995736766e-17, r);
  double r2 = r * r;
  double ss = r * fma(r2, fma(r2, fma(r2, fma(r2, fma(r2,
      -2.505210838544172e-08, 2.7557319223985893e-06),
      -1.984126984126984e-04), 8.333333333333333e-03),
      -0.16666666666666666), 1.0);
  double cc = fma(r2, fma(r2, fma(r2, fma(r2, fma(r2,
      -2.755731922398589e-07, 2.48015873015873e-05),
      -1.3888888888888889e-03), 0.041666666666666664),
      -0.5), 1.0);
  double s_ = (q & 1) ? cc : ss;
  double c_ = (q & 1) ? ss : cc;
  if (q & 2) s_ = -s_;
  if ((q + 1) & 2) c_ = -c_;
  s = s_; c = c_;
}

// ---------------- fused kernel ------------------------------------------------
__global__ void __launch_bounds__(BLK, 4) k_fused(const float* __restrict__ d,
                                                  const float* __restrict__ ang,
                                                  const int* __restrict__ idx,
                                                  float* __restrict__ out,
                                                  int T, KC C) {
  __shared__ __half sv[BLK * ROWH];   // 23552 B
  const int tid = threadIdx.x;
  const int t0 = blockIdx.x * BLK;
  const int t = t0 + tid;

  if (t < T) {
    const int e = __builtin_nontemporal_load(idx + t);
    const float an = __builtin_nontemporal_load(ang + t);
    const float dv = d[e];                         // 4 MB: L2-resident gather

    const float x = dv / 5.0f;
    const float invx = 1.0f / x;
    const float x2 = x * x;
    const float x5 = x2 * x2 * x;
    float env = invx + x5 * fmaf(x, fmaf(x, -21.0f, 48.0f), -28.0f);
    if (x >= 1.0f) env = 0.0f;

    // Legendre P_l(cos an) * env
    const float cth = __cosf(an);
    float mP[NSPH];
    {
      float p0 = 1.f, p1 = cth;
      mP[0] = env; mP[1] = env * cth;
      const float rl[5] = {1.f/2.f, 1.f/3.f, 1.f/4.f, 1.f/5.f, 1.f/6.f};
      #pragma unroll
      for (int l = 2; l < NSPH; ++l) {
        float pn = (fmaf((float)(2*l-1) * cth, p1, -(float)(l-1) * p0)) * rl[l-2];
        mP[l] = env * pn;
        p0 = p1; p1 = pn;
      }
    }

    __half* row = sv + tid * ROWH;

    // ---- l = 0..4 : f32 with HW trig ----
    #pragma unroll
    for (int l = 0; l < 5; ++l) {
      float jv[NRAD];
      #pragma unroll
      for (int n = 0; n < NRAD; ++n) {
        const int i = l * NRAD + n;
        float a = C.zf[i] * x;
        float s = __sinf(a);
        float inva = C.izf[i] * invx;
        float j0 = s * inva;
        float jl;
        if (l == 0) {
          jl = j0;
        } else {
          float c = __cosf(a);
          float j1 = (j0 - c) * inva;
          #pragma unroll
          for (int m = 2; m <= l; ++m) {
            float jn_ = fmaf((float)(2*m-1) * inva, j1, -j0);
            j0 = j1; j1 = jn_;
          }
          jl = j1;
        }
        jv[n] = (C.nyf[i] * jl) * mP[l];
      }
      __half2* dst = (__half2*)(row + l * NRAD);
      dst[0] = __float22half2_rn((float2){jv[0], jv[1]});
      dst[1] = __float22half2_rn((float2){jv[2], jv[3]});
      dst[2] = __float22half2_rn((float2){jv[4], jv[5]});
    }

    // ---- l = 5,6 : f64 ----
    const double xd = (double)x;
    const double invxd = 1.0 / xd;
    #pragma unroll
    for (int l = 5; l < NSPH; ++l) {
      float jv[NRAD];
      #pragma unroll
      for (int n = 0; n < NRAD; ++n) {
        const int k = (l - 5) * NRAD + n;
        double a = C.zd[k] * xd;
        double s, c;
        sincos_d(a, s, c);
        double inva = C.izd[k] * invxd;
        double j0 = s * inva;
        double j1 = (j0 - c) * inva;
        #pragma unroll
        for (int m = 2; m <= l; ++m) {
          double jn_ = fma((double)(2*m-1) * inva, j1, -j0);
          j0 = j1; j1 = jn_;
        }
        jv[n] = (float)(j1 * C.nyd[k]) * mP[l];
      }
      __half2* dst = (__half2*)(row + l * NRAD);
      dst[0] = __float22half2_rn((float2){jv[0], jv[1]});
      dst[1] = __float22half2_rn((float2){jv[2], jv[3]});
      dst[2] = __float22half2_rn((float2){jv[4], jv[5]});
    }
  }
  __syncthreads();

  // ---- coalesced output: LDS(fp16) -> global f32, nt float2 stores ----
  v2f* obase = (v2f*)(out + (size_t)t0 * NJ);
  #pragma unroll
  for (int k = 0; k < 21; ++k) {
    unsigned w = k * BLK + tid;
    unsigned tl = w / 21u;
    unsigned jp = w - tl * 21u;
    if ((int)(t0 + tl) < T) {
      __half2 hh = *(const __half2*)(sv + tl * ROWH + 2 * jp);
      float2 r = __half22float2(hh);
      __builtin_nontemporal_store((v2f){r.x, r.y}, obase + w);
    }
  }
}

// ---------------- host: bessel zeros / norms (f64, deterministic) -------------
static double jn_host(int l, double x) {
  double j0 = sin(x) / x;
  if (l == 0) return j0;
  double j1 = sin(x) / (x * x) - cos(x) / x;
  for (int i = 2; i <= l; ++i) {
    double jn_ = (2 * i - 1) / x * j1 - j0;
    j0 = j1; j1 = jn_;
  }
  return j1;
}

extern "C" void kernel_launch(void* const* d_in, const int* in_sizes, int n_in,
                              void* d_out, int out_size, void* d_ws, size_t ws_size,
                              hipStream_t stream) {
  const float* d   = (const float*)d_in[0];
  const float* ang = (const float*)d_in[1];
  const int*   idx = (const int*)d_in[2];
  float* out = (float*)d_out;
  const int T = in_sizes[1];

  KC C;
  {
    const double PI = 3.14159265358979323846;
    double zeros[NSPH][NRAD];
    double prev[NSPH + NRAD - 1];
    int np_ = NSPH + NRAD - 1;
    for (int i = 0; i < np_; ++i) prev[i] = (i + 1) * PI;
    for (int j = 0; j < NRAD; ++j) zeros[0][j] = prev[j];
    for (int l = 1; l < NSPH; ++l) {
      int nc = np_ - 1;
      double cur[NSPH + NRAD - 1];
      for (int i = 0; i < nc; ++i) {
        double a = prev[i], b = prev[i + 1];
        double fa = jn_host(l, a);
        for (int it = 0; it < 80; ++it) {
          double m = 0.5 * (a + b);
          double fm = jn_host(l, m);
          if ((fm > 0.0) == (fa > 0.0)) { a = m; fa = fm; } else { b = m; }
        }
        cur[i] = 0.5 * (a + b);
      }
      for (int i = 0; i < nc; ++i) prev[i] = cur[i];
      np_ = nc;
      for (int j = 0; j < NRAD; ++j) zeros[l][j] = prev[j];
    }
    for (int l = 0; l < NSPH; ++l) {
      double yn = sqrt((2.0 * l + 1.0) / (4.0 * PI));
      for (int n = 0; n < NRAD; ++n) {
        double z = zeros[l][n];
        double ny = sqrt(2.0) / fabs(jn_host(l + 1, z)) * yn;
        if (l < 5) {
          int i = l * NRAD + n;
          C.zf[i]  = (float)z;
          C.izf[i] = (float)(1.0 / z);
          C.nyf[i] = (float)ny;
        } else {
          int k = (l - 5) * NRAD + n;
          C.zd[k]  = z;
          C.izd[k] = 1.0 / z;
          C.nyd[k] = ny;
        }
      }
    }
  }

  k_fused<<<(T + BLK - 1) / BLK, BLK, 0, stream>>>(d, ang, idx, out, T, C);
}

// Round 5
// 171.104 us; speedup vs baseline: 2.2461x; 1.0706x over previous
//
#include <hip/hip_runtime.h>
#include <hip/hip_bf16.h>
#include <hip/hip_fp16.h>
#include <math.h>

#define NSPH 7
#define NRAD 6
#define NJ 42
#define ROWH 44           // LDS row stride in halves (88 B) -> 22528 B/block, 7 blocks/CU
#define BLK 256

typedef float v2f __attribute__((ext_vector_type(2)));

struct KC {
  float zf[NJ];     // bessel zeros
  float izf[NJ];    // 1/z
  float nyf[NJ];    // NORM * Y_NORM
  float sc5[7];     // series coeffs for j5: j5(a) ~ a^5 * Horner(a^2, sc5)
  float sc6[7];     // series coeffs for j6
};

// ---------------- fused kernel ------------------------------------------------
__global__ void __launch_bounds__(BLK, 4) k_fused(const float* __restrict__ d,
                                                  const float* __restrict__ ang,
                                                  const int* __restrict__ idx,
                                                  float* __restrict__ out,
                                                  int T, KC C) {
  __shared__ __half sv[BLK * ROWH];   // 22528 B
  const int tid = threadIdx.x;
  const int t0 = blockIdx.x * BLK;
  const int t = t0 + tid;

  if (t < T) {
    const int e = __builtin_nontemporal_load(idx + t);
    const float an = __builtin_nontemporal_load(ang + t);
    const float dv = d[e];                         // 4 MB: L2-resident gather

    const float x = dv / 5.0f;
    const float invx = 1.0f / x;
    const float x2 = x * x;
    const float x5 = x2 * x2 * x;
    float env = invx + x5 * fmaf(x, fmaf(x, -21.0f, 48.0f), -28.0f);
    if (x >= 1.0f) env = 0.0f;

    // Legendre P_l(cos an) * env
    const float cth = __cosf(an);
    float mP[NSPH];
    {
      float p0 = 1.f, p1 = cth;
      mP[0] = env; mP[1] = env * cth;
      const float rl[5] = {1.f/2.f, 1.f/3.f, 1.f/4.f, 1.f/5.f, 1.f/6.f};
      #pragma unroll
      for (int l = 2; l < NSPH; ++l) {
        float pn = (fmaf((float)(2*l-1) * cth, p1, -(float)(l-1) * p0)) * rl[l-2];
        mP[l] = env * pn;
        p0 = p1; p1 = pn;
      }
    }

    __half* row = sv + tid * ROWH;

    // ---- l = 0..4 : f32 HW trig + upward recurrence (stable: amp <= ~200) ----
    #pragma unroll
    for (int l = 0; l < 5; ++l) {
      float jv[NRAD];
      #pragma unroll
      for (int n = 0; n < NRAD; ++n) {
        const int i = l * NRAD + n;
        float a = C.zf[i] * x;
        float s = __sinf(a);
        float inva = C.izf[i] * invx;
        float j0 = s * inva;
        float jl;
        if (l == 0) {
          jl = j0;
        } else {
          float c = __cosf(a);
          float j1 = (j0 - c) * inva;
          #pragma unroll
          for (int m = 2; m <= l; ++m) {
            float jn_ = fmaf((float)(2*m-1) * inva, j1, -j0);
            j0 = j1; j1 = jn_;
          }
          jl = j1;
        }
        jv[n] = (C.nyf[i] * jl) * mP[l];
      }
      __half2* dst = (__half2*)(row + l * NRAD);
      dst[0] = __float22half2_rn((float2){jv[0], jv[1]});
      dst[1] = __float22half2_rn((float2){jv[2], jv[3]});
      dst[2] = __float22half2_rn((float2){jv[4], jv[5]});
    }

    // ---- l = 5,6 : f32 stability split ----
    //   a >= 4: upward recurrence (y-amplification 10395/a^5 <= ~10)
    //   a <  4: 7-term power series (no cancellation, rel err ~1e-7)
    #pragma unroll
    for (int l = 5; l < NSPH; ++l) {
      const float* sc = (l == 5) ? C.sc5 : C.sc6;
      float jv[NRAD];
      #pragma unroll
      for (int n = 0; n < NRAD; ++n) {
        const int i = l * NRAD + n;
        float a = C.zf[i] * x;
        float inva = C.izf[i] * invx;
        float s = __sinf(a);
        float c = __cosf(a);
        float j0 = s * inva;
        float j1 = (j0 - c) * inva;
        #pragma unroll
        for (int m = 2; m <= l; ++m) {
          float jn_ = fmaf((float)(2*m-1) * inva, j1, -j0);
          j0 = j1; j1 = jn_;
        }
        float u = a * a;
        float p = fmaf(u, sc[6], sc[5]);
        p = fmaf(u, p, sc[4]);
        p = fmaf(u, p, sc[3]);
        p = fmaf(u, p, sc[2]);
        p = fmaf(u, p, sc[1]);
        p = fmaf(u, p, sc[0]);
        float u2 = u * u;                       // a^4
        float al = (l == 5) ? (u2 * a) : (u2 * u);  // a^5 / a^6
        float jser = al * p;
        float jl = (a < 4.0f) ? jser : j1;
        jv[n] = (C.nyf[i] * jl) * mP[l];
      }
      __half2* dst = (__half2*)(row + l * NRAD);
      dst[0] = __float22half2_rn((float2){jv[0], jv[1]});
      dst[1] = __float22half2_rn((float2){jv[2], jv[3]});
      dst[2] = __float22half2_rn((float2){jv[4], jv[5]});
    }
  }
  __syncthreads();

  // ---- coalesced output: LDS(fp16) -> global f32, nt float2 stores ----
  v2f* obase = (v2f*)(out + (size_t)t0 * NJ);
  #pragma unroll
  for (int k = 0; k < 21; ++k) {
    unsigned w = k * BLK + tid;
    unsigned tl = w / 21u;
    unsigned jp = w - tl * 21u;
    if ((int)(t0 + tl) < T) {
      __half2 hh = *(const __half2*)(sv + tl * ROWH + 2 * jp);
      float2 r = __half22float2(hh);
      __builtin_nontemporal_store((v2f){r.x, r.y}, obase + w);
    }
  }
}

// ---------------- host: bessel zeros / norms (f64, deterministic) -------------
static double jn_host(int l, double x) {
  double j0 = sin(x) / x;
  if (l == 0) return j0;
  double j1 = sin(x) / (x * x) - cos(x) / x;
  for (int i = 2; i <= l; ++i) {
    double jn_ = (2 * i - 1) / x * j1 - j0;
    j0 = j1; j1 = jn_;
  }
  return j1;
}

extern "C" void kernel_launch(void* const* d_in, const int* in_sizes, int n_in,
                              void* d_out, int out_size, void* d_ws, size_t ws_size,
                              hipStream_t stream) {
  const float* d   = (const float*)d_in[0];
  const float* ang = (const float*)d_in[1];
  const int*   idx = (const int*)d_in[2];
  float* out = (float*)d_out;
  const int T = in_sizes[1];

  KC C;
  {
    const double PI = 3.14159265358979323846;
    double zeros[NSPH][NRAD];
    double prev[NSPH + NRAD - 1];
    int np_ = NSPH + NRAD - 1;
    for (int i = 0; i < np_; ++i) prev[i] = (i + 1) * PI;
    for (int j = 0; j < NRAD; ++j) zeros[0][j] = prev[j];
    for (int l = 1; l < NSPH; ++l) {
      int nc = np_ - 1;
      double cur[NSPH + NRAD - 1];
      for (int i = 0; i < nc; ++i) {
        double a = prev[i], b = prev[i + 1];
        double fa = jn_host(l, a);
        for (int it = 0; it < 80; ++it) {
          double m = 0.5 * (a + b);
          double fm = jn_host(l, m);
          if ((fm > 0.0) == (fa > 0.0)) { a = m; fa = fm; } else { b = m; }
        }
        cur[i] = 0.5 * (a + b);
      }
      for (int i = 0; i < nc; ++i) prev[i] = cur[i];
      np_ = nc;
      for (int j = 0; j < NRAD; ++j) zeros[l][j] = prev[j];
    }
    for (int l = 0; l < NSPH; ++l) {
      double yn = sqrt((2.0 * l + 1.0) / (4.0 * PI));
      for (int n = 0; n < NRAD; ++n) {
        int i = l * NRAD + n;
        double z = zeros[l][n];
        C.zf[i]  = (float)z;
        C.izf[i] = (float)(1.0 / z);
        C.nyf[i] = (float)(sqrt(2.0) / fabs(jn_host(l + 1, z)) * yn);
      }
    }
    // series coefficients: j_l(a) = a^l * sum_k coef_k * (a^2)^k,
    // coef_0 = 1/(2l+1)!!, coef_k = -coef_{k-1} / (2k*(2l+2k+1))
    for (int l = 5; l <= 6; ++l) {
      double dfact = 1.0;
      for (int m = 2 * l + 1; m > 1; m -= 2) dfact *= m;
      double ck = 1.0 / dfact;
      float* sc = (l == 5) ? C.sc5 : C.sc6;
      sc[0] = (float)ck;
      for (int k = 1; k < 7; ++k) {
        ck = -ck / (2.0 * k * (2 * l + 2 * k + 1));
        sc[k] = (float)ck;
      }
    }
  }

  k_fused<<<(T + BLK - 1) / BLK, BLK, 0, stream>>>(d, ang, idx, out, T, C);
}